// Round 14
// baseline (296.983 us; speedup 1.0000x reference)
//
#include <hip/hip_runtime.h>

// BitDelta chained layers: per layer W = base + bd*mask (4096x4096 fp32),
// x = x @ W, x [16,4096].  Weight-streaming, memory-bound (134 MB/layer).
//
// R14: 32 waves/CU (2x R10) via PAIRED WAVES sharing a weight stream.
// TPB=256 (4 waves): wave w -> k-range kr=w>>1 (KW=16 rows), x-half
// half=w&1 (8 of 16 x-rows).  The two waves of a pair issue IDENTICAL
// weight addresses (HBM once, partner hits L2); acc[8][4]=32 VGPR +
// single-row depth-1 window (16) => ~60 VGPR, __launch_bounds__(256,8)
// -> 8 waves/SIMD.  Grid 2048 = (KCHUNKS=128) x (NCHUNKS=16) = 8
// blocks/CU, no tail.  Scalar-x (R13-proven).  Epilogue: kr=1 waves dump
// acc to LDS (16 KB), kr=0 waves add and write the [16][256] slab.
// Stage 2: 256 blocks x 64 threads fold 128 slabs (unroll-8 ILP).

#define DD 4096
#define BB 16
#define KW 16                  // k-rows per k-range
#define KC 32                  // k-rows per block (2 k-ranges)
#define VEC 4
#define CT 256                 // cols per block (64 lanes * 4)
#define TPB 256
#define KCHUNKS (DD / KC)      // 128
#define NCHUNKS (DD / CT)      // 16
#define OUT_ELEMS (BB * DD)    // 65536

typedef float f32x4 __attribute__((ext_vector_type(4)));

__global__ __launch_bounds__(TPB, 8)
void bitdelta_layer(const float* __restrict__ x,
                    const float* __restrict__ base,
                    const float* __restrict__ mask,
                    const float* __restrict__ bitdelta,
                    int layer,
                    float* __restrict__ part) {
    __shared__ float red[2][32][64];    // 16 KB pair-reduce buffer

    const int tid = threadIdx.x;
    const int l   = tid & 63;
    const int wid = __builtin_amdgcn_readfirstlane(tid >> 6);  // 0..3
    const int kr   = wid >> 1;          // k-range in block (0/1)
    const int half = wid & 1;           // x-row half (0/1)

    const int bid    = blockIdx.x;
    const int cchunk = bid & (NCHUNKS - 1);
    const int kchunk = bid >> 4;        // 0..127

    const int c0 = cchunk * CT + l * VEC;
    const int k0 = kchunk * KC + kr * KW;     // wave-uniform

    const float bd = bitdelta[layer];

    const float* wb = base + (size_t)k0 * DD + c0;
    const float* wm = mask + (size_t)k0 * DD + c0;
    const float* xp = x + (size_t)(half * 8) * DD + k0;   // wave-uniform

    float acc[8][VEC];
#pragma unroll
    for (int r = 0; r < 8; ++r)
#pragma unroll
        for (int c = 0; c < VEC; ++c) acc[r][c] = 0.0f;

    // Single-row depth-1 window: 2 float4 loads in flight (1 KB granule).
    float4 b0 = *reinterpret_cast<const float4*>(wb);
    float4 m0 = *reinterpret_cast<const float4*>(wm);

#pragma unroll
    for (int kw = 0; kw < KW; ++kw) {
        float4 nb, nm;
        if (kw + 1 < KW) {   // compile-time after full unroll
            nb = *reinterpret_cast<const float4*>(wb + (size_t)(kw + 1) * DD);
            nm = *reinterpret_cast<const float4*>(wm + (size_t)(kw + 1) * DD);
        }

        const float w0 = fmaf(bd, m0.x, b0.x);
        const float w1 = fmaf(bd, m0.y, b0.y);
        const float w2 = fmaf(bd, m0.z, b0.z);
        const float w3 = fmaf(bd, m0.w, b0.w);

#pragma unroll
        for (int r = 0; r < 8; ++r) {
            const float xv = xp[r * DD + kw];   // wave-uniform s_load
            acc[r][0] = fmaf(xv, w0, acc[r][0]);
            acc[r][1] = fmaf(xv, w1, acc[r][1]);
            acc[r][2] = fmaf(xv, w2, acc[r][2]);
            acc[r][3] = fmaf(xv, w3, acc[r][3]);
        }

        if (kw + 1 < KW) { b0 = nb; m0 = nm; }
    }

    // Pair-reduce: kr=1 waves dump, kr=0 waves add (same half).
    if (kr == 1) {
#pragma unroll
        for (int r = 0; r < 8; ++r)
#pragma unroll
            for (int c = 0; c < VEC; ++c)
                red[half][r * VEC + c][l] = acc[r][c];
    }
    __syncthreads();

    if (kr == 0) {
#pragma unroll
        for (int r = 0; r < 8; ++r)
#pragma unroll
            for (int c = 0; c < VEC; ++c)
                acc[r][c] += red[half][r * VEC + c][l];

        // Write slab rows half*8..half*8+7.
        float* pp = part + (size_t)kchunk * OUT_ELEMS + (size_t)(half * 8) * DD + c0;
#pragma unroll
        for (int r = 0; r < 8; ++r) {
            f32x4 v = { acc[r][0], acc[r][1], acc[r][2], acc[r][3] };
            *reinterpret_cast<f32x4*>(pp + (size_t)r * DD) = v;
        }
    }
}

// Stage 2: out[e] = sum_k part[k][e].  256 blocks x 64 threads: one wave
// per CU; lane owns one float4 (1 KB contiguous per slab-load); 128
// independent slab loads per thread, unroll-8 ILP (mostly L3 hits).
__global__ __launch_bounds__(64)
void reduce_partials(const float* __restrict__ part, float* __restrict__ out) {
    const int idx = (blockIdx.x * 64 + threadIdx.x) * 4;   // float4 base
    f32x4 a = *reinterpret_cast<const f32x4*>(&part[idx]);
#pragma unroll 8
    for (int k = 1; k < KCHUNKS; ++k) {
        const f32x4 p = *reinterpret_cast<const f32x4*>(
            &part[(size_t)k * OUT_ELEMS + idx]);
        a += p;
    }
    *reinterpret_cast<f32x4*>(&out[idx]) = a;
}

extern "C" void kernel_launch(void* const* d_in, const int* in_sizes, int n_in,
                              void* d_out, int out_size, void* d_ws, size_t ws_size,
                              hipStream_t stream) {
    const float* x    = (const float*)d_in[0];   // [16,4096]
    const float* base = (const float*)d_in[1];   // [4,4096,4096]
    const float* mask = (const float*)d_in[2];   // [4,4096,4096]
    const float* bd   = (const float*)d_in[3];   // [4]
    float* out = (float*)d_out;                  // [16,4096] fp32

    float* part = (float*)d_ws;                  // 128 x 65536 floats = 32 MB
    float* y0   = part + (size_t)KCHUNKS * OUT_ELEMS;
    float* y1   = y0 + OUT_ELEMS;

    const size_t layer_stride = (size_t)DD * DD;
    const int    grid1 = KCHUNKS * NCHUNKS;      // 2048
    const int    grid2 = OUT_ELEMS / (64 * 4);   // 256 blocks, 64 threads

    bitdelta_layer<<<grid1, TPB, 0, stream>>>(x, base, mask, bd, 0, part);
    reduce_partials<<<grid2, 64, 0, stream>>>(part, y0);

    bitdelta_layer<<<grid1, TPB, 0, stream>>>(y0, base + 1 * layer_stride,
                                              mask + 1 * layer_stride, bd, 1, part);
    reduce_partials<<<grid2, 64, 0, stream>>>(part, y1);

    bitdelta_layer<<<grid1, TPB, 0, stream>>>(y1, base + 2 * layer_stride,
                                              mask + 2 * layer_stride, bd, 2, part);
    reduce_partials<<<grid2, 64, 0, stream>>>(part, y0);

    bitdelta_layer<<<grid1, TPB, 0, stream>>>(y0, base + 3 * layer_stride,
                                              mask + 3 * layer_stride, bd, 3, part);
    reduce_partials<<<grid2, 64, 0, stream>>>(part, out);
}

// Round 15
// 179.307 us; speedup vs baseline: 1.6563x; 1.6563x over previous
//
#include <hip/hip_runtime.h>

// BitDelta chained layers: per layer W = base + bd*mask (4096x4096 fp32),
// x = x @ W, x [16,4096].  Weight-streaming, memory-bound (134 MB/layer).
//
// R15 = R10's wave-level stream EXACTLY (KW=16 k-rows/wave, float4 = 1 KB
// granule, depth-1 window prefetch, wave-uniform scalar-x), regrouped as
// TPB=512 (8 waves), KC=128 -> KCHUNKS=32: partial traffic halves
// (16->8 MB/layer) and stage-2 reads halve (16.25->8.06 MB).  Grid 512 =
// 2 blocks/CU -> 16 waves/CU, the R7/R10-proven operating point.
// Epilogue: 8-wave 4-round LDS tree (28 KB), wave 0 writes the slab.
// __launch_bounds__(512,4) caps VGPR at 128 (body ~110, no spill).
// Stage 2: 256 blocks x 64 threads fold 32 slabs.

#define DD 4096
#define BB 16
#define KW 16                  // k-rows per wave (unchanged from R10)
#define NW 8                   // waves per block
#define KC (KW * NW)           // 128 k-rows per block
#define VEC 4
#define CT 256                 // cols per block (64 lanes * 4)
#define TPB 512                // 8 waves
#define KCHUNKS (DD / KC)      // 32
#define NCHUNKS (DD / CT)      // 16
#define OUT_ELEMS (BB * DD)    // 65536

typedef float f32x4 __attribute__((ext_vector_type(4)));

__global__ __launch_bounds__(TPB, 4)
void bitdelta_layer(const float* __restrict__ x,
                    const float* __restrict__ base,
                    const float* __restrict__ mask,
                    const float* __restrict__ bitdelta,
                    int layer,
                    float* __restrict__ part) {
    __shared__ float red[16][7 * 64];   // 28 KB reduce buffer

    const int tid = threadIdx.x;
    const int l   = tid & 63;
    const int wid = __builtin_amdgcn_readfirstlane(tid >> 6);  // 0..7

    const int bid    = blockIdx.x;
    const int cchunk = bid & (NCHUNKS - 1);
    const int kchunk = bid >> 4;              // 0..31

    const int c0 = cchunk * CT + l * VEC;
    const int k0 = kchunk * KC + wid * KW;    // wave-uniform

    const float bd = bitdelta[layer];

    const float* wb = base + (size_t)k0 * DD + c0;
    const float* wm = mask + (size_t)k0 * DD + c0;
    const float* xp = x + k0;                 // wave-uniform base

    float acc[BB][VEC];
#pragma unroll
    for (int r = 0; r < BB; ++r)
#pragma unroll
        for (int c = 0; c < VEC; ++c) acc[r][c] = 0.0f;

    // ---- streaming k-loop: BYTE-IDENTICAL pattern to R10 ----
    float4 b0 = *reinterpret_cast<const float4*>(wb);
    float4 b1 = *reinterpret_cast<const float4*>(wb + DD);
    float4 m0 = *reinterpret_cast<const float4*>(wm);
    float4 m1 = *reinterpret_cast<const float4*>(wm + DD);

#pragma unroll
    for (int kw = 0; kw < KW; kw += 2) {
        float4 nb0, nb1, nm0, nm1;
        if (kw + 2 < KW) {   // compile-time after full unroll
            const float* pb = wb + (size_t)(kw + 2) * DD;
            const float* pm = wm + (size_t)(kw + 2) * DD;
            nb0 = *reinterpret_cast<const float4*>(pb);
            nb1 = *reinterpret_cast<const float4*>(pb + DD);
            nm0 = *reinterpret_cast<const float4*>(pm);
            nm1 = *reinterpret_cast<const float4*>(pm + DD);
        }

        const float w00 = fmaf(bd, m0.x, b0.x);
        const float w01 = fmaf(bd, m0.y, b0.y);
        const float w02 = fmaf(bd, m0.z, b0.z);
        const float w03 = fmaf(bd, m0.w, b0.w);
        const float w10 = fmaf(bd, m1.x, b1.x);
        const float w11 = fmaf(bd, m1.y, b1.y);
        const float w12 = fmaf(bd, m1.z, b1.z);
        const float w13 = fmaf(bd, m1.w, b1.w);

#pragma unroll
        for (int r = 0; r < BB; ++r) {
            // Wave-uniform -> scalar loads on the SMEM pipe.
            const float xv0 = xp[r * DD + kw];
            const float xv1 = xp[r * DD + kw + 1];
            acc[r][0] = fmaf(xv0, w00, acc[r][0]);
            acc[r][1] = fmaf(xv0, w01, acc[r][1]);
            acc[r][2] = fmaf(xv0, w02, acc[r][2]);
            acc[r][3] = fmaf(xv0, w03, acc[r][3]);
            acc[r][0] = fmaf(xv1, w10, acc[r][0]);
            acc[r][1] = fmaf(xv1, w11, acc[r][1]);
            acc[r][2] = fmaf(xv1, w12, acc[r][2]);
            acc[r][3] = fmaf(xv1, w13, acc[r][3]);
        }

        if (kw + 2 < KW) { b0 = nb0; b1 = nb1; m0 = nm0; m1 = nm1; }
    }

    // 8-wave LDS reduce, four rounds of 16 elements (28 KB, conflict-free).
#pragma unroll
    for (int t = 0; t < 4; ++t) {
        if (t) __syncthreads();
        if (wid != 0) {
#pragma unroll
            for (int e = 0; e < 16; ++e) {
                const int r = t * 4 + (e >> 2), c = e & 3;
                red[e][(wid - 1) * 64 + l] = acc[r][c];
            }
        }
        __syncthreads();
        if (wid == 0) {
#pragma unroll
            for (int e = 0; e < 16; ++e) {
                const int r = t * 4 + (e >> 2), c = e & 3;
                float s = acc[r][c];
#pragma unroll
                for (int w = 0; w < 7; ++w) s += red[e][w * 64 + l];
                acc[r][c] = s;
            }
        }
    }

    // Wave 0 writes the block partial: [16][256] slab, float4 stores.
    if (wid == 0) {
        float* pp = part + (size_t)kchunk * OUT_ELEMS;
#pragma unroll
        for (int r = 0; r < BB; ++r) {
            f32x4 v = { acc[r][0], acc[r][1], acc[r][2], acc[r][3] };
            *reinterpret_cast<f32x4*>(&pp[r * DD + c0]) = v;
        }
    }
}

// Stage 2: out[e] = sum_k part[k][e].  256 blocks x 64 threads: one wave
// per CU; lane owns one float4 (1 KB contiguous per slab-load); 32
// independent slab loads per thread (deep ILP).
__global__ __launch_bounds__(64)
void reduce_partials(const float* __restrict__ part, float* __restrict__ out) {
    const int idx = (blockIdx.x * 64 + threadIdx.x) * 4;   // float4 base
    f32x4 a = *reinterpret_cast<const f32x4*>(&part[idx]);
#pragma unroll
    for (int k = 1; k < KCHUNKS; ++k) {
        const f32x4 p = *reinterpret_cast<const f32x4*>(
            &part[(size_t)k * OUT_ELEMS + idx]);
        a += p;
    }
    *reinterpret_cast<f32x4*>(&out[idx]) = a;
}

extern "C" void kernel_launch(void* const* d_in, const int* in_sizes, int n_in,
                              void* d_out, int out_size, void* d_ws, size_t ws_size,
                              hipStream_t stream) {
    const float* x    = (const float*)d_in[0];   // [16,4096]
    const float* base = (const float*)d_in[1];   // [4,4096,4096]
    const float* mask = (const float*)d_in[2];   // [4,4096,4096]
    const float* bd   = (const float*)d_in[3];   // [4]
    float* out = (float*)d_out;                  // [16,4096] fp32

    float* part = (float*)d_ws;                  // 32 x 65536 floats = 8 MB
    float* y0   = part + (size_t)KCHUNKS * OUT_ELEMS;
    float* y1   = y0 + OUT_ELEMS;

    const size_t layer_stride = (size_t)DD * DD;
    const int    grid1 = KCHUNKS * NCHUNKS;      // 512 blocks x 512 threads
    const int    grid2 = OUT_ELEMS / (64 * 4);   // 256 blocks x 64 threads

    bitdelta_layer<<<grid1, TPB, 0, stream>>>(x, base, mask, bd, 0, part);
    reduce_partials<<<grid2, 64, 0, stream>>>(part, y0);

    bitdelta_layer<<<grid1, TPB, 0, stream>>>(y0, base + 1 * layer_stride,
                                              mask + 1 * layer_stride, bd, 1, part);
    reduce_partials<<<grid2, 64, 0, stream>>>(part, y1);

    bitdelta_layer<<<grid1, TPB, 0, stream>>>(y1, base + 2 * layer_stride,
                                              mask + 2 * layer_stride, bd, 2, part);
    reduce_partials<<<grid2, 64, 0, stream>>>(part, y0);

    bitdelta_layer<<<grid1, TPB, 0, stream>>>(y0, base + 3 * layer_stride,
                                              mask + 3 * layer_stride, bd, 3, part);
    reduce_partials<<<grid2, 64, 0, stream>>>(part, out);
}